// Round 12
// baseline (1825.896 us; speedup 1.0000x reference)
//
#include <hip/hip_runtime.h>
#include <hip/hip_fp16.h>

#define TT 2048
#define BB 256
#define HH 64
#define II 60
#define OO 12
#define LL 3

typedef _Float16 h2    __attribute__((ext_vector_type(2)));
typedef _Float16 f16x8 __attribute__((ext_vector_type(8)));
typedef float    f32x4 __attribute__((ext_vector_type(4)));

__device__ __forceinline__ float sigf(float x)   { return 1.f / (1.f + __expf(-x)); }
__device__ __forceinline__ float tanhf2(float x) { return 2.f / (1.f + __expf(-2.f * x)) - 1.f; }

// ---- pre-pass: x [B,T,60] fp32 -> xh [B,T,64] f16 (zero-padded) ----
__global__ __launch_bounds__(256)
void xcvt(const float* __restrict__ x, _Float16* __restrict__ xh) {
  long v = (long)blockIdx.x * 256 + threadIdx.x;   // over B*T*64
  int col = (int)(v & 63);
  long rowi = v >> 6;
  float f = (col < II) ? x[rowi * II + col] : 0.f;
  xh[v] = (_Float16)f;
}

// ---- fused 3-layer wavefront LSTM: 1 barrier/phase, in-register combine ----
// Block b = batch b (256 blocks). 768 threads = 3 teams x 4 waves (team l =
// layer l). N-partition: wave wv owns ALL 4 gate types for units
// [16wv,16wv+16): weight row n = nt*64 + wv*16 + (lane&15). With M=1 MFMA
// (broadcast A row), thread (lane&15=row) gets gate nt for its unit in
// acc[nt][0] -> i,f,g~,o all in-register -> combine in the same wave, no
// gate exchange, no second barrier. Phase s, team l: t = s-l;
//   read A rows (x(t) from regs for l=0, else HBF[l-1][(s-1)&3]; own
//   h from HBF[l][(s-1)&3]) -> 16x mfma_f32_16x16x32_f16 -> combine ->
//   publish h to HBF[l][s&3] (kgrp==0 lanes) -> ONE barrier.
// c-state: replicated across the 4 kgrp groups (identical deterministic
// values; D rows are bit-identical since A rows are). K-map used identically
// for A and B fragments => K-permutation invariant; N/D map HW-proven (r8/11).
__global__ __launch_bounds__(768, 1)
void lstm3_fused(const _Float16* __restrict__ xh,
                 _Float16* __restrict__ hs,
                 const float* __restrict__ Wih0, const float* __restrict__ Whh0,
                 const float* __restrict__ bih0, const float* __restrict__ bhh0,
                 const float* __restrict__ Wih1, const float* __restrict__ Whh1,
                 const float* __restrict__ bih1, const float* __restrict__ bhh1,
                 const float* __restrict__ Wih2, const float* __restrict__ Whh2,
                 const float* __restrict__ bih2, const float* __restrict__ bhh2,
                 const float* __restrict__ h0, const float* __restrict__ c0,
                 float* __restrict__ hn, float* __restrict__ cn) {
  const int b    = blockIdx.x;
  const int tid  = threadIdx.x;
  const int l    = tid >> 8;
  const int g    = tid & 255;
  const int lane = g & 63;
  const int wv   = g >> 6;
  const int row  = lane & 15;
  const int kgrp = lane >> 4;
  const int unit = wv * 16 + row;     // this thread's hidden unit

  __shared__ __align__(16) _Float16 HBF[LL][4][HH];

  const float* Wih = (l == 0) ? Wih0 : (l == 1) ? Wih1 : Wih2;
  const float* Whh = (l == 0) ? Whh0 : (l == 1) ? Whh1 : Whh2;
  const float* bih = (l == 0) ? bih0 : (l == 1) ? bih1 : bih2;
  const float* bhh = (l == 0) ? bhh0 : (l == 1) ? bhh1 : bhh2;
  const int IN = (l == 0) ? II : HH;

  // resident B-fragments: n = nt*64 + unit; k = kt*32 + kgrp*8 + j
  f16x8 wb[4][4];                    // [nt][kt]
  float biasv[4];
#pragma unroll
  for (int nt = 0; nt < 4; nt++) {
    const int n = nt * 64 + unit;
    biasv[nt] = bih[n] + bhh[n];
#pragma unroll
    for (int kt = 0; kt < 4; kt++) {
      f16x8 f;
#pragma unroll
      for (int j = 0; j < 8; j++) {
        const int k = kt * 32 + kgrp * 8 + j;
        float v;
        if (k < 64) v = (k < IN) ? Wih[(size_t)n * IN + k] : 0.f;
        else        v = Whh[(size_t)n * HH + (k - 64)];
        f[j] = (_Float16)v;
      }
      wb[nt][kt] = f;
    }
  }

  float creg = c0[(l * BB + b) * HH + unit];
  {
    float hv = h0[(l * BB + b) * HH + unit];
    if (kgrp == 0) HBF[l][(l + 3) & 3][unit] = (_Float16)hv;  // seed slot (l-1)&3
  }
  __syncthreads();

  const _Float16* xb = xh + (size_t)b * TT * 64 + kgrp * 8;
  auto ldx = [&](int t, int c) -> f16x8 {
    return *(const f16x8*)(xb + (size_t)t * 64 + c * 32);
  };

  f16x8 XA0, XA1, XB0, XB1;
  if (l == 0) {
    XA0 = ldx(0, 0); XA1 = ldx(0, 1);   // x(0): phase 0
    XB0 = ldx(1, 0); XB1 = ldx(1, 1);   // x(1): phase 1
  }

  auto phase = [&](int s, f16x8& X0, f16x8& X1) {
    const int t = s - l;
    if (t >= 0 && t < TT) {
      const int ps = (s + 3) & 3;       // (s-1)&3
      f16x8 a0, a1;
      if (l == 0) { a0 = X0; a1 = X1; }
      else {
        a0 = *(const f16x8*)&HBF[l - 1][ps][kgrp * 8];
        a1 = *(const f16x8*)&HBF[l - 1][ps][32 + kgrp * 8];
      }
      f16x8 a2 = *(const f16x8*)&HBF[l][ps][kgrp * 8];
      f16x8 a3 = *(const f16x8*)&HBF[l][ps][32 + kgrp * 8];

      f32x4 acc[4];
#pragma unroll
      for (int nt = 0; nt < 4; nt++) {
        acc[nt] = (f32x4){biasv[nt], biasv[nt], biasv[nt], biasv[nt]};
        acc[nt] = __builtin_amdgcn_mfma_f32_16x16x32_f16(a0, wb[nt][0], acc[nt], 0, 0, 0);
        acc[nt] = __builtin_amdgcn_mfma_f32_16x16x32_f16(a1, wb[nt][1], acc[nt], 0, 0, 0);
        acc[nt] = __builtin_amdgcn_mfma_f32_16x16x32_f16(a2, wb[nt][2], acc[nt], 0, 0, 0);
        acc[nt] = __builtin_amdgcn_mfma_f32_16x16x32_f16(a3, wb[nt][3], acc[nt], 0, 0, 0);
      }

      // in-register combine: this thread's unit has all 4 gates in acc[*][0]
      float gi = acc[0][0], gf = acc[1][0], gg = acc[2][0], go = acc[3][0];
      creg = sigf(gf) * creg + sigf(gi) * tanhf2(gg);
      float hv = sigf(go) * tanhf2(creg);

      if (kgrp == 0) {
        HBF[l][s & 3][unit] = (_Float16)hv;
        if (l == 2) hs[((size_t)b * TT + t) * HH + unit] = (_Float16)hv;
        if (t == TT - 1) {
          hn[(l * BB + b) * HH + unit] = hv;
          cn[(l * BB + b) * HH + unit] = creg;
        }
      }
    }
    if (l == 0) {                       // refill: consumed at phase s+2
      int rt = s + 2; if (rt > TT - 1) rt = TT - 1;
      X0 = ldx(rt, 0); X1 = ldx(rt, 1);
    }
    __syncthreads();                    // HBF[.][s&3] published
  };

  for (int s = 0; s < TT + 2; s += 2) {
    phase(s,     XA0, XA1);
    phase(s + 1, XB0, XB1);
  }
}

// ---- output projection: y[b,t,:] = W_out @ h_row + b_out ----
__global__ __launch_bounds__(256)
void oproj(const _Float16* __restrict__ hs,
           const float* __restrict__ Wout,
           const float* __restrict__ bout,
           float* __restrict__ y) {
  __shared__ float Wo[OO * HH];
  __shared__ float bo[OO];
  const int tid = threadIdx.x;
  for (int i = tid; i < OO * HH; i += 256) Wo[i] = Wout[i];
  if (tid < OO) bo[tid] = bout[tid];
  __syncthreads();

  const long r = (long)blockIdx.x * 256 + tid;  // r = b*T + t
  const uint4* h4 = (const uint4*)(hs + r * HH);
  float hf[HH];
#pragma unroll
  for (int jj = 0; jj < 8; jj++) {
    uint4 q = h4[jj];
    h2 p0 = __builtin_bit_cast(h2, q.x), p1 = __builtin_bit_cast(h2, q.y);
    h2 p2 = __builtin_bit_cast(h2, q.z), p3 = __builtin_bit_cast(h2, q.w);
    hf[8 * jj + 0] = (float)p0[0]; hf[8 * jj + 1] = (float)p0[1];
    hf[8 * jj + 2] = (float)p1[0]; hf[8 * jj + 3] = (float)p1[1];
    hf[8 * jj + 4] = (float)p2[0]; hf[8 * jj + 5] = (float)p2[1];
    hf[8 * jj + 6] = (float)p3[0]; hf[8 * jj + 7] = (float)p3[1];
  }

  float out[OO];
#pragma unroll
  for (int o = 0; o < OO; o++) {
    float a0 = bo[o], a1 = 0.f, a2 = 0.f, a3 = 0.f;
#pragma unroll
    for (int k = 0; k < HH; k += 4) {
      a0 += hf[k + 0] * Wo[o * HH + k + 0];
      a1 += hf[k + 1] * Wo[o * HH + k + 1];
      a2 += hf[k + 2] * Wo[o * HH + k + 2];
      a3 += hf[k + 3] * Wo[o * HH + k + 3];
    }
    out[o] = (a0 + a1) + (a2 + a3);
  }
  float4* yp = (float4*)(y + r * OO);
#pragma unroll
  for (int q = 0; q < 3; q++)
    yp[q] = make_float4(out[4 * q], out[4 * q + 1], out[4 * q + 2], out[4 * q + 3]);
}

extern "C" void kernel_launch(void* const* d_in, const int* in_sizes, int n_in,
                              void* d_out, int out_size, void* d_ws, size_t ws_size,
                              hipStream_t stream) {
  const float* x    = (const float*)d_in[0];
  const float* h0   = (const float*)d_in[1];
  const float* c0   = (const float*)d_in[2];
  const float* Wih0 = (const float*)d_in[3];
  const float* Whh0 = (const float*)d_in[4];
  const float* bih0 = (const float*)d_in[5];
  const float* bhh0 = (const float*)d_in[6];
  const float* Wih1 = (const float*)d_in[7];
  const float* Whh1 = (const float*)d_in[8];
  const float* bih1 = (const float*)d_in[9];
  const float* bhh1 = (const float*)d_in[10];
  const float* Wih2 = (const float*)d_in[11];
  const float* Whh2 = (const float*)d_in[12];
  const float* bih2 = (const float*)d_in[13];
  const float* bhh2 = (const float*)d_in[14];
  const float* Wout = (const float*)d_in[15];
  const float* bout = (const float*)d_in[16];

  float* y  = (float*)d_out;
  float* hn = y + (size_t)BB * TT * OO;
  float* cn = hn + (size_t)LL * BB * HH;

  // ws layout (round-11 proven): xh (f16 padded x) at 0; hs at +128MiB
  _Float16* xh = (_Float16*)d_ws;
  _Float16* hs = (_Float16*)((char*)d_ws + (size_t)BB * TT * HH * 2 * sizeof(_Float16));

  xcvt<<<dim3(BB * TT * HH / 256), dim3(256), 0, stream>>>(x, xh);
  lstm3_fused<<<dim3(BB), dim3(768), 0, stream>>>(xh, hs,
      Wih0, Whh0, bih0, bhh0, Wih1, Whh1, bih1, bhh1, Wih2, Whh2, bih2, bhh2,
      h0, c0, hn, cn);
  oproj<<<dim3(BB * TT / 256), dim3(256), 0, stream>>>(hs, Wout, bout, y);
}